// Round 13
// baseline (9208.174 us; speedup 1.0000x reference)
//
#include <hip/hip_runtime.h>
#include <math.h>

// Problem dims
#define SLEN 256
#define BSZ  128
#define DIN  128
#define HSZ  512
#define HH2  1024
#define GG3  1536
#define OSZ  25

typedef _Float16 h8 __attribute__((ext_vector_type(8)));
typedef float    f4 __attribute__((ext_vector_type(4)));

// 256 blocks x 1024 threads, 1 block/CU.
// Roles: b<64: W1(+c-state) | b<128: W2 | b<192: W3(+PART) | b<256: gates(+h-state)
#define NBLK 256
#define NTHR 1024

#define SM_F16 24576

// Barrier storage: 5 counters + 5 x 4 replicated epoch lines (64-dword lines)
#define CLINE 64
#define NCTR ((8 + 20) * CLINE)

struct P_t {
  const float *x, *noise, *b_cin, *b1, *b2, *b3, *w4, *b4, *b_ih, *b_hh, *w_out, *b_out;
  _Float16 *WT1, *WT2, *WT3, *WTih, *WThh, *WTcin;
  _Float16 *CIN, *COMlo, *Z1, *Z2, *HF16;   // COMlo/HF16: x2 parity buffers
  float *LOGI, *GX, *GH, *PART, *HF32;      // GX/GH/PART: x2 parity buffers
  unsigned *CTR;
  float *out;
};

// ---------------- agent-scope (sc1) coherent primitives ----------------
__device__ __forceinline__ void lic_load16(h8* d, const _Float16* p) {
  asm volatile(
      "global_load_dwordx4 %0, %16, off sc1\n\t"
      "global_load_dwordx4 %1, %16, off offset:64 sc1\n\t"
      "global_load_dwordx4 %2, %16, off offset:128 sc1\n\t"
      "global_load_dwordx4 %3, %16, off offset:192 sc1\n\t"
      "global_load_dwordx4 %4, %16, off offset:256 sc1\n\t"
      "global_load_dwordx4 %5, %16, off offset:320 sc1\n\t"
      "global_load_dwordx4 %6, %16, off offset:384 sc1\n\t"
      "global_load_dwordx4 %7, %16, off offset:448 sc1\n\t"
      "global_load_dwordx4 %8, %16, off offset:512 sc1\n\t"
      "global_load_dwordx4 %9, %16, off offset:576 sc1\n\t"
      "global_load_dwordx4 %10, %16, off offset:640 sc1\n\t"
      "global_load_dwordx4 %11, %16, off offset:704 sc1\n\t"
      "global_load_dwordx4 %12, %16, off offset:768 sc1\n\t"
      "global_load_dwordx4 %13, %16, off offset:832 sc1\n\t"
      "global_load_dwordx4 %14, %16, off offset:896 sc1\n\t"
      "global_load_dwordx4 %15, %16, off offset:960 sc1\n\t"
      "s_waitcnt vmcnt(0)"
      : "=&v"(d[0]), "=&v"(d[1]), "=&v"(d[2]), "=&v"(d[3]),
        "=&v"(d[4]), "=&v"(d[5]), "=&v"(d[6]), "=&v"(d[7]),
        "=&v"(d[8]), "=&v"(d[9]), "=&v"(d[10]), "=&v"(d[11]),
        "=&v"(d[12]), "=&v"(d[13]), "=&v"(d[14]), "=&v"(d[15])
      : "v"(p) : "memory");
}
__device__ __forceinline__ void lic_load8(h8* d, const _Float16* p) {
  asm volatile(
      "global_load_dwordx4 %0, %8, off sc1\n\t"
      "global_load_dwordx4 %1, %8, off offset:64 sc1\n\t"
      "global_load_dwordx4 %2, %8, off offset:128 sc1\n\t"
      "global_load_dwordx4 %3, %8, off offset:192 sc1\n\t"
      "global_load_dwordx4 %4, %8, off offset:256 sc1\n\t"
      "global_load_dwordx4 %5, %8, off offset:320 sc1\n\t"
      "global_load_dwordx4 %6, %8, off offset:384 sc1\n\t"
      "global_load_dwordx4 %7, %8, off offset:448 sc1\n\t"
      "s_waitcnt vmcnt(0)"
      : "=&v"(d[0]), "=&v"(d[1]), "=&v"(d[2]), "=&v"(d[3]),
        "=&v"(d[4]), "=&v"(d[5]), "=&v"(d[6]), "=&v"(d[7])
      : "v"(p) : "memory");
}
__device__ __forceinline__ void lic_load4f4(f4* d, const float* p) {
  asm volatile(
      "global_load_dwordx4 %0, %4, off sc1\n\t"
      "global_load_dwordx4 %1, %4, off offset:16 sc1\n\t"
      "global_load_dwordx4 %2, %4, off offset:32 sc1\n\t"
      "global_load_dwordx4 %3, %4, off offset:48 sc1\n\t"
      "s_waitcnt vmcnt(0)"
      : "=&v"(d[0]), "=&v"(d[1]), "=&v"(d[2]), "=&v"(d[3])
      : "v"(p) : "memory");
}
__device__ __forceinline__ float lic_load4(const float* p) {
  float v;
  asm volatile("global_load_dword %0, %1, off sc1\n\ts_waitcnt vmcnt(0)"
               : "=v"(v) : "v"(p) : "memory");
  return v;
}
__device__ __forceinline__ unsigned lic_loadu(const unsigned* p) {
  unsigned v;
  asm volatile("global_load_dword %0, %1, off sc1\n\ts_waitcnt vmcnt(0)"
               : "=v"(v) : "v"(p) : "memory");
  return v;
}
__device__ __forceinline__ void lic_load_gates(float* o, const float* gxm, const float* ghm) {
  asm volatile(
      "global_load_dword %0, %6, off offset:-2048 sc1\n\t"
      "global_load_dword %1, %6, off sc1\n\t"
      "global_load_dword %2, %6, off offset:2048 sc1\n\t"
      "global_load_dword %3, %7, off offset:-2048 sc1\n\t"
      "global_load_dword %4, %7, off sc1\n\t"
      "global_load_dword %5, %7, off offset:2048 sc1\n\t"
      "s_waitcnt vmcnt(0)"
      : "=&v"(o[0]), "=&v"(o[1]), "=&v"(o[2]),
        "=&v"(o[3]), "=&v"(o[4]), "=&v"(o[5])
      : "v"(gxm), "v"(ghm) : "memory");
}
__device__ __forceinline__ void lic_store2(_Float16* p, _Float16 v) {
  union { _Float16 h; unsigned short s; } u; u.h = v;
  unsigned w = u.s;
  asm volatile("global_store_short %0, %1, off sc1" :: "v"(p), "v"(w) : "memory");
}
__device__ __forceinline__ void lic_store4(float* p, float v) {
  asm volatile("global_store_dword %0, %1, off sc1" :: "v"(p), "v"(v) : "memory");
}
__device__ __forceinline__ void lic_store16(_Float16* p, h8 v) {
  asm volatile("global_store_dwordx4 %0, %1, off sc1" :: "v"(p), "v"(v) : "memory");
}
__device__ __forceinline__ void lic_storeu(unsigned* p, unsigned v) {
  asm volatile("global_store_dword %0, %1, off sc1" :: "v"(p), "v"(v) : "memory");
}

// ---------------- barrier: counter arrivals + replicated epoch flag ----------------
__device__ __forceinline__ void blk_arrive(unsigned* cnt, unsigned* epo, unsigned last_old) {
  asm volatile("s_waitcnt vmcnt(0)" ::: "memory");
  __syncthreads();
  if (threadIdx.x == 0) {
    unsigned old = __hip_atomic_fetch_add(cnt, 1u, __ATOMIC_RELAXED, __HIP_MEMORY_SCOPE_AGENT);
    if (old == last_old) {
      unsigned ep = (last_old + 1u) >> 6;
      lic_storeu(epo, ep);
      lic_storeu(epo + CLINE, ep);
      lic_storeu(epo + 2 * CLINE, ep);
      lic_storeu(epo + 3 * CLINE, ep);
    }
  }
}
// HOT WAIT (R13): all 16 waves poll a replica line via lane 0 and burn a
// dependent-FMA chain between polls. Rationale: the kernel is ~95% idle which
// plausibly parks DVFS at the idle clock floor, multiplying every RTT ~10x
// (per-step time was invariant to hop count/contention/scope — only a global
// latency scale fits). Burning VALU keeps the CU "busy" for the governor.
__device__ __forceinline__ void blk_wait(const unsigned* epo4, unsigned target, float* sink) {
  const int lane = threadIdx.x & 63;
  const int wv = threadIdx.x >> 6;
  const unsigned* line = epo4 + ((((int)blockIdx.x >> 2) + wv) & 3) * CLINE;
  float x0 = 1.0000001f, x1 = 0.9999999f;
  for (;;) {
    unsigned v = 0;
    if (lane == 0) v = lic_loadu(line);
    v = (unsigned)__shfl((int)v, 0);
    if (v >= target) break;
#pragma unroll
    for (int i = 0; i < 64; ++i) {
      x0 = __builtin_fmaf(x0, x1, 1e-20f);
      x1 = __builtin_fmaf(x1, x0, -1e-20f);
    }
  }
  if (x0 + x1 == 123.456f) *(volatile float*)sink = x0;  // unreachable; keeps burn alive
  __syncthreads();
}

// ---------------- MFMA helpers ----------------
__device__ __forceinline__ f4 mfma16(h8 a, h8 b, f4 c) {
  return __builtin_amdgcn_mfma_f32_16x16x32_f16(a, b, c, 0, 0, 0);
}
__device__ __forceinline__ f4 gemm_sc512(const _Float16* ap, const _Float16* Bs, int lane) {
  const _Float16* bp = Bs + lane * 8;
  h8 A[16];
  lic_load16(A, ap);
  f4 acc = {0.f, 0.f, 0.f, 0.f};
#pragma unroll
  for (int c = 0; c < 16; ++c) acc = mfma16(A[c], *(const h8*)(bp + c * 512), acc);
  return acc;
}
__device__ __forceinline__ void gemm2_sc512(const _Float16* ap, const _Float16* B0,
                                            const _Float16* B1, int lane, f4& o0, f4& o1) {
  const _Float16* b0 = B0 + lane * 8;
  const _Float16* b1 = B1 + lane * 8;
  h8 A[8];
  f4 x = {0.f, 0.f, 0.f, 0.f}, y = x;
  lic_load8(A, ap);
#pragma unroll
  for (int c = 0; c < 8; ++c) {
    x = mfma16(A[c], *(const h8*)(b0 + c * 512), x);
    y = mfma16(A[c], *(const h8*)(b1 + c * 512), y);
  }
  lic_load8(A, ap + 256);
#pragma unroll
  for (int c = 0; c < 8; ++c) {
    x = mfma16(A[c], *(const h8*)(b0 + (c + 8) * 512), x);
    y = mfma16(A[c], *(const h8*)(b1 + (c + 8) * 512), y);
  }
  o0 = x; o1 = y;
}

// ---------------- setup kernels (proven) ----------------
__global__ __launch_bounds__(256) void transpose_cvt(const float* __restrict__ src,
    _Float16* __restrict__ dst, int K, int N) {
  __shared__ float tl[32][33];
  int nt = N >> 5;
  int bx = blockIdx.x % nt, by = blockIdx.x / nt;
  int n0 = bx << 5, k0 = by << 5;
  int tx = threadIdx.x & 31, ty = threadIdx.x >> 5;
#pragma unroll
  for (int i = 0; i < 4; ++i) {
    int r = ty + (i << 3);
    tl[r][tx] = src[(size_t)(k0 + r) * N + n0 + tx];
  }
  __syncthreads();
#pragma unroll
  for (int i = 0; i < 4; ++i) {
    int r = ty + (i << 3);
    dst[(size_t)(n0 + r) * K + k0 + tx] = (_Float16)tl[tx][r];
  }
}

__global__ __launch_bounds__(256) void cin_kernel(P_t P) {
  int tid = blockIdx.x * blockDim.x + threadIdx.x;
  if (tid < SLEN * BSZ) {
    float u = P.noise[tid];
    P.LOGI[tid] = logf(u) - log1pf(-u);
  }
  int gw = tid >> 6, lane = tid & 63;
  int nw = (gridDim.x * blockDim.x) >> 6;
  int ml = lane & 15, q = lane >> 4;
  const int MT = (SLEN * BSZ) / 16;
  for (int tt = gw; tt < MT * 8; tt += nw) {
    int mt = tt & (MT - 1), nt = tt / MT;
    int m0 = mt * 16, n0 = nt * 64;
    int m = m0 + ml, b = m & 127, s = m >> 7;
    const float* ap = P.x + ((size_t)b * SLEN + s) * DIN + q * 8;
    const _Float16* bp = P.WTcin + (size_t)(n0 + ml) * DIN + q * 8;
    f4 a0 = {0,0,0,0}, a1 = a0, a2 = a0, a3 = a0;
#pragma unroll
    for (int k = 0; k < DIN; k += 32) {
      f4 lo = *(const f4*)(ap + k);
      f4 hi = *(const f4*)(ap + k + 4);
      h8 av;
      av[0] = (_Float16)lo[0]; av[1] = (_Float16)lo[1];
      av[2] = (_Float16)lo[2]; av[3] = (_Float16)lo[3];
      av[4] = (_Float16)hi[0]; av[5] = (_Float16)hi[1];
      av[6] = (_Float16)hi[2]; av[7] = (_Float16)hi[3];
      a0 = __builtin_amdgcn_mfma_f32_16x16x32_f16(av, *(const h8*)(bp + k),          a0, 0,0,0);
      a1 = __builtin_amdgcn_mfma_f32_16x16x32_f16(av, *(const h8*)(bp + 16*DIN + k), a1, 0,0,0);
      a2 = __builtin_amdgcn_mfma_f32_16x16x32_f16(av, *(const h8*)(bp + 32*DIN + k), a2, 0,0,0);
      a3 = __builtin_amdgcn_mfma_f32_16x16x32_f16(av, *(const h8*)(bp + 48*DIN + k), a3, 0,0,0);
    }
#pragma unroll
    for (int r = 0; r < 4; ++r) {
      int row = m0 + q * 4 + r;
      int c0 = n0 + ml;
      P.CIN[(size_t)row * HSZ + c0     ] = (_Float16)tanhf(a0[r] + P.b_cin[c0]);
      P.CIN[(size_t)row * HSZ + c0 + 16] = (_Float16)tanhf(a1[r] + P.b_cin[c0 + 16]);
      P.CIN[(size_t)row * HSZ + c0 + 32] = (_Float16)tanhf(a2[r] + P.b_cin[c0 + 32]);
      P.CIN[(size_t)row * HSZ + c0 + 48] = (_Float16)tanhf(a3[r] + P.b_cin[c0 + 48]);
    }
  }
}

__global__ __launch_bounds__(256) void init_kernel(P_t P) {
  int idx = blockIdx.x * 256 + threadIdx.x;
  if (idx < BSZ * HSZ) {
    P.HF32[idx] = 0.f;
    P.HF16[idx] = (_Float16)0.f;
    P.HF16[idx + BSZ * HSZ] = (_Float16)0.f;
    P.COMlo[idx] = (_Float16)0.f;
    P.COMlo[idx + BSZ * HSZ] = (_Float16)0.f;
  }
  if (idx < NCTR) P.CTR[idx] = 0u;
}

// ---------------- main persistent dataflow kernel ----------------
__global__ __launch_bounds__(NTHR) void rnn_main(P_t P) {
  __shared__ __align__(16) _Float16 sm[SM_F16];
  __shared__ f4 red[8][64];
  __shared__ float sred[8];
  const int tid = threadIdx.x;
  const int b = blockIdx.x;
  const int lane = tid & 63;
  const int wv = tid >> 6;          // 0..15
  const int ml = lane & 15, q = lane >> 4;

  unsigned* CNT = P.CTR;
  unsigned* EPO = P.CTR + 8 * CLINE;
#define CNTB(k)  (CNT + (k) * CLINE)
#define EPOB(k)  (EPO + (k) * 4 * CLINE)
  // k: 0=CTA(z1,c) 1=CTB(z2) 2=CTC(PART) 3=CTD(gates) 4=CTE(h-state)
  float* snk = &sred[3];  // unused slot; unreachable-write sink for hot-wait

  // ---- stage weights into LDS, fragment-major ----
  if (b < 192) {
    const _Float16* W = (b < 64) ? P.WT1 : (b < 128) ? P.WT2 : P.WT3;
    const int j16 = b & 63;
#pragma unroll
    for (int rp = 0; rp < 2; ++rp) {
      int idx = tid + rp * 1024;
      int kk = idx >> 6, ln = idx & 63;
      int mlw = ln & 15, qw = ln >> 4;
      *(h8*)(sm + idx * 8) =
          *(const h8*)(W + (size_t)(16 * j16 + mlw) * HH2 + kk * 32 + qw * 8);
    }
  } else {
    const int i = b - 192;
#pragma unroll
    for (int s = 0; s < 3; ++s) {
      int g = 3 * i + s;
      const _Float16* src = (g < 96) ? (P.WTih + (size_t)(16 * g) * HSZ)
                                     : (P.WThh + (size_t)(16 * (g - 96)) * HSZ);
      int idx = tid;
      int kk = idx >> 6, ln = idx & 63;
      int mlw = ln & 15, qw = ln >> 4;
      *(h8*)(sm + s * 8192 + idx * 8) =
          *(const h8*)(src + (size_t)mlw * HSZ + kk * 32 + qw * 8);
    }
  }
  __syncthreads();

  if (b < 64) {
    // ======== W1 role: owns c-state in registers; 3-hop critical path ========
    const int tt = wv & 7, hf = wv >> 3;
    const int R = 16 * tt + ml;
    const int colb = 16 * b + ml;
    const float bia = P.b1[colb];
    const float b4v = P.b4[0];
    f4 cf[16];
#pragma unroll
    for (int i = 0; i < 16; ++i) cf[i] = (f4){0.f, 0.f, 0.f, 0.f};
    float n_r = 0.f;
    const bool pub = (tt == (b >> 3)) && ((ml >> 1) == (b & 7));  // rows 2b,2b+1

    for (int t = 0; t <= SLEN; ++t) {
      blk_wait(EPOB(2), (unsigned)t, snk);                       // alpha(t-1) partials
      blk_wait(EPOB(4), (unsigned)(t > 0 ? t - 1 : 0), snk);     // COMlo[t&1] WAR
      if (t > 0) {
        f4 pr[4];
        lic_load4f4(pr, P.PART + (size_t)((t - 1) & 1) * BSZ * 64 + (size_t)R * 64 + q * 16);
        float s = pr[0][0] + pr[0][1] + pr[0][2] + pr[0][3]
                + pr[1][0] + pr[1][1] + pr[1][2] + pr[1][3]
                + pr[2][0] + pr[2][1] + pr[2][2] + pr[2][3]
                + pr[3][0] + pr[3][1] + pr[3][2] + pr[3][3];
        s += __shfl_xor(s, 16); s += __shfl_xor(s, 32);
        float lg = (s + b4v + P.LOGI[(size_t)(t - 1) * BSZ + R]) * 10.0f;
        float alpha = 1.f / (1.f + expf(-lg));
        float om = 1.f - alpha;
        float nom = n_r * om, nnew = nom + 1.f;
        n_r = nnew;
        const _Float16* cinp = P.CIN + ((size_t)(t - 1) * BSZ + R) * HSZ + hf * 256 + q * 8;
#pragma unroll
        for (int i = 0; i < 8; ++i) {
          h8 ci = *(const h8*)(cinp + i * 32);
#pragma unroll
          for (int j = 0; j < 4; ++j) {
            cf[2 * i][j]     = (cf[2 * i][j]     * nom + (float)ci[j])     / nnew;
            cf[2 * i + 1][j] = (cf[2 * i + 1][j] * nom + (float)ci[4 + j]) / nnew;
          }
        }
      }
      if (pub) {
        _Float16* cp = P.COMlo + (size_t)(t & 1) * BSZ * HSZ
                     + (size_t)R * HSZ + hf * 256 + q * 8;
#pragma unroll
        for (int i = 0; i < 8; ++i) {
          h8 hv;
#pragma unroll
          for (int j = 0; j < 4; ++j) {
            hv[j]     = (_Float16)cf[2 * i][j];
            hv[4 + j] = (_Float16)cf[2 * i + 1][j];
          }
          lic_store16(cp + i * 32, hv);
        }
      }
      if (t == SLEN) { blk_arrive(CNTB(0), EPOB(0), 64u * (unsigned)(SLEN + 1) - 1u); break; }
      const _Float16* bfc = sm + (size_t)(hf * 8) * 512 + lane * 8;
      const _Float16* bfn = sm + (size_t)(16 + hf * 8) * 512 + lane * 8;
      const _Float16* cin2 = P.CIN + ((size_t)t * BSZ + R) * HSZ + hf * 256 + q * 8;
      f4 a = {0.f, 0.f, 0.f, 0.f};
#pragma unroll
      for (int i = 0; i < 8; ++i) {
        h8 av;
#pragma unroll
        for (int j = 0; j < 4; ++j) {
          av[j]     = (_Float16)cf[2 * i][j];
          av[4 + j] = (_Float16)cf[2 * i + 1][j];
        }
        a = mfma16(av, *(const h8*)(bfc + (size_t)i * 512), a);
      }
#pragma unroll
      for (int i = 0; i < 8; ++i)
        a = mfma16(*(const h8*)(cin2 + i * 32), *(const h8*)(bfn + (size_t)i * 512), a);
      if (hf) red[tt][lane] = a;
      __syncthreads();
      if (!hf) {
        f4 o = red[tt][lane];
#pragma unroll
        for (int j = 0; j < 4; ++j)
          lic_store2(P.Z1 + (size_t)(tt * 16 + q * 4 + j) * HH2 + colb,
                     (_Float16)fmaxf(a[j] + o[j] + bia, 0.f));
      }
      blk_arrive(CNTB(0), EPOB(0), 64u * (unsigned)(t + 1) - 1u);
    }
  } else if (b < 192) {
    // ======== W2 / W3 roles ========
    const int role = (b < 128) ? 1 : 2;
    const int cb = (role == 1) ? b - 64 : b - 128;
    const int colb = 16 * cb + ml;
    const float bia = (role == 1) ? P.b2[colb] : P.b3[colb];
    const float w4v = (role == 2) ? P.w4[colb] : 0.f;
    const int r = wv & 7, half = wv >> 3, m0 = r * 16;

    for (int t = 0; t < SLEN; ++t) {
      if (role == 1) {
        blk_wait(EPOB(0), (unsigned)(t + 1), snk);
      } else {
        blk_wait(EPOB(1), (unsigned)(t + 1), snk);
        blk_wait(EPOB(4), (unsigned)(t > 0 ? t - 1 : 0), snk);   // PART[t&1] WAR
      }
      const _Float16* A = (role == 1) ? P.Z1 : P.Z2;
      f4 a = gemm_sc512(A + (size_t)(m0 + ml) * HH2 + half * 512 + q * 8,
                        sm + (size_t)half * 16 * 512, lane);
      if (wv >= 8) red[r][lane] = a;
      __syncthreads();
      if (wv < 8) {
        f4 o = red[r][lane];
        if (role == 1) {
#pragma unroll
          for (int j = 0; j < 4; ++j)
            lic_store2(P.Z2 + (size_t)(m0 + q * 4 + j) * HH2 + colb,
                       (_Float16)fmaxf(a[j] + o[j] + bia, 0.f));
        } else {
#pragma unroll
          for (int j = 0; j < 4; ++j) {
            float v = fmaxf(a[j] + o[j] + bia, 0.f) * w4v;
            v += __shfl_xor(v, 1); v += __shfl_xor(v, 2);
            v += __shfl_xor(v, 4); v += __shfl_xor(v, 8);
            if (ml == 0)
              lic_store4(P.PART + (size_t)(t & 1) * BSZ * 64
                         + (size_t)(m0 + q * 4 + j) * 64 + cb, v);
          }
        }
      }
      if (role == 1) blk_arrive(CNTB(1), EPOB(1), 64u * (unsigned)(t + 1) - 1u);
      else           blk_arrive(CNTB(2), EPOB(2), 64u * (unsigned)(t + 1) - 1u);
    }
  } else {
    // ======== gate role: gx/gh GEMMs + h-state for rows 2i,2i+1 ========
    const int i = b - 192;
    const bool isgx = (i < 32);
    const float* bsrc = isgx ? P.b_ih : P.b_hh;
    float* gbase = isgx ? P.GX : P.GH;
    const int i0 = isgx ? 3 * i : 3 * (i - 32);
    const int c0 = 16 * i0 + ml, c1 = 16 * (i0 + 1) + ml, c2 = 16 * (i0 + 2) + ml;
    const float bi0 = bsrc[c0], bi1 = bsrc[c1], bi2 = bsrc[c2];

    for (int t = 0; t < SLEN; ++t) {
      if (isgx) {
        blk_wait(EPOB(0), (unsigned)(t + 1), snk);               // c(t-1) in COMlo[t&1]
        blk_wait(EPOB(4), (unsigned)(t > 0 ? t - 1 : 0), snk);   // GX[t&1] WAR
      } else {
        blk_wait(EPOB(4), (unsigned)t, snk);                     // h(t-1) in HF16[t&1]
      }
      const _Float16* Ag = (isgx ? P.COMlo : P.HF16) + (size_t)(t & 1) * BSZ * HSZ;
      float* gdst = gbase + (size_t)(t & 1) * BSZ * GG3;
      if (wv < 8) {
        const int m0 = wv * 16;
        f4 a0, a1;
        gemm2_sc512(Ag + (size_t)(m0 + ml) * HSZ + q * 8, sm, sm + 8192, lane, a0, a1);
#pragma unroll
        for (int j = 0; j < 4; ++j) {
          size_t rw = (size_t)(m0 + q * 4 + j) * GG3;
          lic_store4(gdst + rw + c0, a0[j] + bi0);
          lic_store4(gdst + rw + c1, a1[j] + bi1);
        }
      } else {
        const int m0 = (wv - 8) * 16;
        f4 a2 = gemm_sc512(Ag + (size_t)(m0 + ml) * HSZ + q * 8, sm + 2 * 8192, lane);
#pragma unroll
        for (int j = 0; j < 4; ++j)
          lic_store4(gdst + (size_t)(m0 + q * 4 + j) * GG3 + c2, a2[j] + bi2);
      }
      blk_arrive(CNTB(3), EPOB(3), 64u * (unsigned)(t + 1) - 1u);
      blk_wait(EPOB(2), (unsigned)(t + 1), snk);   // alpha(t) partials
      blk_wait(EPOB(3), (unsigned)(t + 1), snk);   // gx(t)/gh(t)
      if (wv < 2) {
        int row = 2 * i + wv;
        float v = lic_load4(P.PART + (size_t)(t & 1) * BSZ * 64 + (size_t)row * 64 + lane);
#pragma unroll
        for (int off = 32; off > 0; off >>= 1) v += __shfl_xor(v, off);
        if (lane == 0) {
          float lg = (v + P.b4[0] + P.LOGI[t * BSZ + row]) * 10.0f;
          float alpha = 1.f / (1.f + expf(-lg));
          sred[wv * 4 + 0] = alpha;
          sred[wv * 4 + 1] = 1.f - alpha;
        }
      }
      __syncthreads();
      {
        int rr = tid >> 9, col = tid & 511, row = 2 * i + rr;
        float alpha = sred[rr * 4], om = sred[rr * 4 + 1];
        const float* gx = P.GX + (size_t)(t & 1) * BSZ * GG3;
        const float* gh = P.GH + (size_t)(t & 1) * BSZ * GG3;
        float g[6];
        lic_load_gates(g, gx + (size_t)row * GG3 + col + 512,
                          gh + (size_t)row * GG3 + col + 512);
        float rgate = 1.f / (1.f + expf(-(g[0] + g[3])));
        float zgate = 1.f / (1.f + expf(-(g[1] + g[4])));
        float ngate = tanhf(g[2] + rgate * g[5]);
        size_t ho = (size_t)row * HSZ + col;
        float h_old = P.HF32[ho];
        float hg = (1.f - zgate) * ngate + zgate * h_old;
        float hnew = h_old * om + alpha * hg;
        P.HF32[ho] = hnew;
        lic_store2(P.HF16 + (size_t)((t + 1) & 1) * BSZ * HSZ + ho, (_Float16)hnew);
      }
      blk_arrive(CNTB(4), EPOB(4), 64u * (unsigned)(t + 1) - 1u);
    }

    // ---- tail: final gate GEMMs (c(255), h(255); parity 0) + final GRU + out ----
    if (isgx) blk_wait(EPOB(0), (unsigned)(SLEN + 1), snk);
    else      blk_wait(EPOB(4), (unsigned)SLEN, snk);
    {
      const _Float16* Ag = (isgx ? P.COMlo : P.HF16) + 0;  // parity SLEN&1 == 0
      float* gdst = gbase;                                  // parity 0
      if (wv < 8) {
        const int m0 = wv * 16;
        f4 a0, a1;
        gemm2_sc512(Ag + (size_t)(m0 + ml) * HSZ + q * 8, sm, sm + 8192, lane, a0, a1);
#pragma unroll
        for (int j = 0; j < 4; ++j) {
          size_t rw = (size_t)(m0 + q * 4 + j) * GG3;
          lic_store4(gdst + rw + c0, a0[j] + bi0);
          lic_store4(gdst + rw + c1, a1[j] + bi1);
        }
      } else {
        const int m0 = (wv - 8) * 16;
        f4 a2 = gemm_sc512(Ag + (size_t)(m0 + ml) * HSZ + q * 8, sm + 2 * 8192, lane);
#pragma unroll
        for (int j = 0; j < 4; ++j)
          lic_store4(gdst + (size_t)(m0 + q * 4 + j) * GG3 + c2, a2[j] + bi2);
      }
    }
    blk_arrive(CNTB(3), EPOB(3), 64u * (unsigned)(SLEN + 1) - 1u);
    blk_wait(EPOB(3), (unsigned)(SLEN + 1), snk);
    __syncthreads();  // weights done; reuse sm as float hfin[1024]
    {
      float* hf = (float*)sm;
      int rr = tid >> 9, col = tid & 511, row = 2 * i + rr;
      float g[6];
      lic_load_gates(g, P.GX + (size_t)row * GG3 + col + 512,
                        P.GH + (size_t)row * GG3 + col + 512);
      float rgate = 1.f / (1.f + expf(-(g[0] + g[3])));
      float zgate = 1.f / (1.f + expf(-(g[1] + g[4])));
      float ngate = tanhf(g[2] + rgate * g[5]);
      float h_old = P.HF32[(size_t)row * HSZ + col];
      hf[tid] = (1.f - zgate) * ngate + zgate * h_old;
    }
    __syncthreads();
    if (wv < 2) {
      const float* hf = (const float*)sm;
      int row = 2 * i + wv;
      float accs[OSZ];
#pragma unroll
      for (int c = 0; c < OSZ; ++c) accs[c] = 0.f;
#pragma unroll
      for (int j = 0; j < 8; ++j) {
        float hv = hf[wv * 512 + lane * 8 + j];
        const float* wr = P.w_out + (size_t)(lane * 8 + j) * OSZ;
#pragma unroll
        for (int c = 0; c < OSZ; ++c) accs[c] += hv * wr[c];
      }
#pragma unroll
      for (int c = 0; c < OSZ; ++c) {
        float v = accs[c];
#pragma unroll
        for (int off = 32; off > 0; off >>= 1) v += __shfl_xor(v, off);
        if (lane == 0) P.out[row * OSZ + c] = v + P.b_out[c];
      }
    }
  }
}

// ---------------- host ----------------
extern "C" void kernel_launch(void* const* d_in, const int* in_sizes, int n_in,
                              void* d_out, int out_size, void* d_ws, size_t ws_size,
                              hipStream_t stream) {
  const float* x     = (const float*)d_in[0];
  const float* noise = (const float*)d_in[1];
  const float* w_cin = (const float*)d_in[2];
  const float* b_cin = (const float*)d_in[3];
  const float* w1    = (const float*)d_in[4];
  const float* b1    = (const float*)d_in[5];
  const float* w2    = (const float*)d_in[6];
  const float* b2    = (const float*)d_in[7];
  const float* w3    = (const float*)d_in[8];
  const float* b3    = (const float*)d_in[9];
  const float* w4    = (const float*)d_in[10];
  const float* b4    = (const float*)d_in[11];
  const float* w_ih  = (const float*)d_in[12];
  const float* b_ih  = (const float*)d_in[13];
  const float* w_hh  = (const float*)d_in[14];
  const float* b_hh  = (const float*)d_in[15];
  const float* w_out = (const float*)d_in[16];
  const float* b_out = (const float*)d_in[17];

  char* ws = (char*)d_ws;
  size_t off = 0;
  auto alloc = [&](size_t bytes) -> void* {
    void* p = ws + off;
    off = (off + bytes + 255) & ~(size_t)255;
    return p;
  };

  P_t P;
  P.x = x; P.noise = noise; P.b_cin = b_cin; P.b1 = b1; P.b2 = b2; P.b3 = b3;
  P.w4 = w4; P.b4 = b4; P.b_ih = b_ih; P.b_hh = b_hh; P.w_out = w_out; P.b_out = b_out;
  P.WT1   = (_Float16*)alloc((size_t)HH2 * HH2 * 2);
  P.WT2   = (_Float16*)alloc((size_t)HH2 * HH2 * 2);
  P.WT3   = (_Float16*)alloc((size_t)HH2 * HH2 * 2);
  P.WTih  = (_Float16*)alloc((size_t)GG3 * HSZ * 2);
  P.WThh  = (_Float16*)alloc((size_t)GG3 * HSZ * 2);
  P.WTcin = (_Float16*)alloc((size_t)HSZ * DIN * 2);
  P.CIN   = (_Float16*)alloc((size_t)SLEN * BSZ * HSZ * 2);
  P.COMlo = (_Float16*)alloc((size_t)2 * BSZ * HSZ * 2);
  P.Z1    = (_Float16*)alloc((size_t)BSZ * HH2 * 2);
  P.Z2    = (_Float16*)alloc((size_t)BSZ * HH2 * 2);
  P.HF16  = (_Float16*)alloc((size_t)2 * BSZ * HSZ * 2);
  P.LOGI  = (float*)alloc((size_t)SLEN * BSZ * 4);
  P.GX    = (float*)alloc((size_t)2 * BSZ * GG3 * 4);
  P.GH    = (float*)alloc((size_t)2 * BSZ * GG3 * 4);
  P.PART  = (float*)alloc((size_t)2 * BSZ * 64 * 4);
  P.HF32  = (float*)alloc((size_t)BSZ * HSZ * 4);
  P.CTR   = (unsigned*)alloc(NCTR * 4);
  P.out   = (float*)d_out;

  transpose_cvt<<<(HH2 / 32) * (HH2 / 32), 256, 0, stream>>>(w1, P.WT1, HH2, HH2);
  transpose_cvt<<<(HH2 / 32) * (HH2 / 32), 256, 0, stream>>>(w2, P.WT2, HH2, HH2);
  transpose_cvt<<<(HH2 / 32) * (HH2 / 32), 256, 0, stream>>>(w3, P.WT3, HH2, HH2);
  transpose_cvt<<<(GG3 / 32) * (HSZ / 32), 256, 0, stream>>>(w_ih, P.WTih, HSZ, GG3);
  transpose_cvt<<<(GG3 / 32) * (HSZ / 32), 256, 0, stream>>>(w_hh, P.WThh, HSZ, GG3);
  transpose_cvt<<<(HSZ / 32) * (DIN / 32), 256, 0, stream>>>(w_cin, P.WTcin, DIN, HSZ);

  cin_kernel<<<1024, 256, 0, stream>>>(P);
  init_kernel<<<256, 256, 0, stream>>>(P);
  rnn_main<<<NBLK, NTHR, 0, stream>>>(P);
}

// Round 14
// 8379.488 us; speedup vs baseline: 1.0989x; 1.0989x over previous
//
#include <hip/hip_runtime.h>
#include <math.h>

// Problem dims
#define SLEN 256
#define BSZ  128
#define DIN  128
#define HSZ  512
#define HH2  1024
#define GG3  1536
#define OSZ  25

typedef _Float16 h8 __attribute__((ext_vector_type(8)));
typedef float    f4 __attribute__((ext_vector_type(4)));

// 256 blocks x 1024 threads, 1 block/CU.
// Roles: b<64: W1(+c-state) | b<128: W2 | b<192: W3(+PART) | b<256: gates(+h-state)
#define NBLK 256
#define NTHR 1024

#define SM_F16 24576

// Barrier storage: 5 counters + 5 x 4 replicated epoch lines (64-dword lines)
#define CLINE 64
#define NCTR ((8 + 20) * CLINE)

struct P_t {
  const float *x, *noise, *b_cin, *b1, *b2, *b3, *w4, *b4, *b_ih, *b_hh, *w_out, *b_out;
  _Float16 *WT1, *WT2, *WT3, *WTih, *WThh, *WTcin;
  // STEP-VERSIONED (write-once addresses; producers sc1, consumers CACHED):
  _Float16 *CIN, *COMlo /*[SLEN+1]*/, *Z1 /*[SLEN]*/, *Z2 /*[SLEN]*/, *HF16 /*[SLEN+1]*/;
  float *LOGI, *GX, *GH, *PART, *HF32;      // GX/GH/PART: x2 parity, sc1 plane
  unsigned *CTR;
  float *out;
};

// ---------------- agent-scope (sc1) coherent primitives (flags + small data) ----------------
__device__ __forceinline__ void lic_load4f4(f4* d, const float* p) {
  asm volatile(
      "global_load_dwordx4 %0, %4, off sc1\n\t"
      "global_load_dwordx4 %1, %4, off offset:16 sc1\n\t"
      "global_load_dwordx4 %2, %4, off offset:32 sc1\n\t"
      "global_load_dwordx4 %3, %4, off offset:48 sc1\n\t"
      "s_waitcnt vmcnt(0)"
      : "=&v"(d[0]), "=&v"(d[1]), "=&v"(d[2]), "=&v"(d[3])
      : "v"(p) : "memory");
}
__device__ __forceinline__ float lic_load4(const float* p) {
  float v;
  asm volatile("global_load_dword %0, %1, off sc1\n\ts_waitcnt vmcnt(0)"
               : "=v"(v) : "v"(p) : "memory");
  return v;
}
__device__ __forceinline__ unsigned lic_loadu(const unsigned* p) {
  unsigned v;
  asm volatile("global_load_dword %0, %1, off sc1\n\ts_waitcnt vmcnt(0)"
               : "=v"(v) : "v"(p) : "memory");
  return v;
}
__device__ __forceinline__ void lic_load_gates(float* o, const float* gxm, const float* ghm) {
  asm volatile(
      "global_load_dword %0, %6, off offset:-2048 sc1\n\t"
      "global_load_dword %1, %6, off sc1\n\t"
      "global_load_dword %2, %6, off offset:2048 sc1\n\t"
      "global_load_dword %3, %7, off offset:-2048 sc1\n\t"
      "global_load_dword %4, %7, off sc1\n\t"
      "global_load_dword %5, %7, off offset:2048 sc1\n\t"
      "s_waitcnt vmcnt(0)"
      : "=&v"(o[0]), "=&v"(o[1]), "=&v"(o[2]),
        "=&v"(o[3]), "=&v"(o[4]), "=&v"(o[5])
      : "v"(gxm), "v"(ghm) : "memory");
}
__device__ __forceinline__ void lic_store2(_Float16* p, _Float16 v) {
  union { _Float16 h; unsigned short s; } u; u.h = v;
  unsigned w = u.s;
  asm volatile("global_store_short %0, %1, off sc1" :: "v"(p), "v"(w) : "memory");
}
__device__ __forceinline__ void lic_store4(float* p, float v) {
  asm volatile("global_store_dword %0, %1, off sc1" :: "v"(p), "v"(v) : "memory");
}
__device__ __forceinline__ void lic_store16(_Float16* p, h8 v) {
  asm volatile("global_store_dwordx4 %0, %1, off sc1" :: "v"(p), "v"(v) : "memory");
}
__device__ __forceinline__ void lic_storeu(unsigned* p, unsigned v) {
  asm volatile("global_store_dword %0, %1, off sc1" :: "v"(p), "v"(v) : "memory");
}

// ---------------- barrier: counter arrivals + replicated epoch flag ----------------
__device__ __forceinline__ void blk_arrive(unsigned* cnt, unsigned* epo, unsigned last_old) {
  asm volatile("s_waitcnt vmcnt(0)" ::: "memory");
  __syncthreads();
  if (threadIdx.x == 0) {
    unsigned old = __hip_atomic_fetch_add(cnt, 1u, __ATOMIC_RELAXED, __HIP_MEMORY_SCOPE_AGENT);
    if (old == last_old) {
      unsigned ep = (last_old + 1u) >> 6;
      lic_storeu(epo, ep);
      lic_storeu(epo + CLINE, ep);
      lic_storeu(epo + 2 * CLINE, ep);
      lic_storeu(epo + 3 * CLINE, ep);
    }
  }
}
__device__ __forceinline__ void blk_wait(const unsigned* epo_line, unsigned target) {
  if (threadIdx.x == 0) {
    while (lic_loadu(epo_line) < target) __builtin_amdgcn_s_sleep(1);
  }
  __syncthreads();
}

// ---------------- MFMA helpers ----------------
__device__ __forceinline__ f4 mfma16(h8 a, h8 b, f4 c) {
  return __builtin_amdgcn_mfma_f32_16x16x32_f16(a, b, c, 0, 0, 0);
}
// K=512, A via CACHED loads (write-once versioned buffer: no stale-line hazard;
// L2 shares each 128B line across the ~8 same-role blocks on the XCD).
__device__ __forceinline__ f4 gemm_c512(const _Float16* ap, const _Float16* Bs, int lane) {
  const _Float16* bp = Bs + lane * 8;
  f4 acc = {0.f, 0.f, 0.f, 0.f};
#pragma unroll
  for (int c = 0; c < 16; ++c)
    acc = mfma16(*(const h8*)(ap + c * 32), *(const h8*)(bp + c * 512), acc);
  return acc;
}
__device__ __forceinline__ void gemm2_c512(const _Float16* ap, const _Float16* B0,
                                           const _Float16* B1, int lane, f4& o0, f4& o1) {
  const _Float16* b0 = B0 + lane * 8;
  const _Float16* b1 = B1 + lane * 8;
  f4 x = {0.f, 0.f, 0.f, 0.f}, y = x;
#pragma unroll
  for (int c = 0; c < 16; ++c) {
    h8 av = *(const h8*)(ap + c * 32);
    x = mfma16(av, *(const h8*)(b0 + c * 512), x);
    y = mfma16(av, *(const h8*)(b1 + c * 512), y);
  }
  o0 = x; o1 = y;
}

// ---------------- setup kernels (proven) ----------------
__global__ __launch_bounds__(256) void transpose_cvt(const float* __restrict__ src,
    _Float16* __restrict__ dst, int K, int N) {
  __shared__ float tl[32][33];
  int nt = N >> 5;
  int bx = blockIdx.x % nt, by = blockIdx.x / nt;
  int n0 = bx << 5, k0 = by << 5;
  int tx = threadIdx.x & 31, ty = threadIdx.x >> 5;
#pragma unroll
  for (int i = 0; i < 4; ++i) {
    int r = ty + (i << 3);
    tl[r][tx] = src[(size_t)(k0 + r) * N + n0 + tx];
  }
  __syncthreads();
#pragma unroll
  for (int i = 0; i < 4; ++i) {
    int r = ty + (i << 3);
    dst[(size_t)(n0 + r) * K + k0 + tx] = (_Float16)tl[tx][r];
  }
}

__global__ __launch_bounds__(256) void cin_kernel(P_t P) {
  int tid = blockIdx.x * blockDim.x + threadIdx.x;
  if (tid < SLEN * BSZ) {
    float u = P.noise[tid];
    P.LOGI[tid] = logf(u) - log1pf(-u);
  }
  int gw = tid >> 6, lane = tid & 63;
  int nw = (gridDim.x * blockDim.x) >> 6;
  int ml = lane & 15, q = lane >> 4;
  const int MT = (SLEN * BSZ) / 16;
  for (int tt = gw; tt < MT * 8; tt += nw) {
    int mt = tt & (MT - 1), nt = tt / MT;
    int m0 = mt * 16, n0 = nt * 64;
    int m = m0 + ml, b = m & 127, s = m >> 7;
    const float* ap = P.x + ((size_t)b * SLEN + s) * DIN + q * 8;
    const _Float16* bp = P.WTcin + (size_t)(n0 + ml) * DIN + q * 8;
    f4 a0 = {0,0,0,0}, a1 = a0, a2 = a0, a3 = a0;
#pragma unroll
    for (int k = 0; k < DIN; k += 32) {
      f4 lo = *(const f4*)(ap + k);
      f4 hi = *(const f4*)(ap + k + 4);
      h8 av;
      av[0] = (_Float16)lo[0]; av[1] = (_Float16)lo[1];
      av[2] = (_Float16)lo[2]; av[3] = (_Float16)lo[3];
      av[4] = (_Float16)hi[0]; av[5] = (_Float16)hi[1];
      av[6] = (_Float16)hi[2]; av[7] = (_Float16)hi[3];
      a0 = __builtin_amdgcn_mfma_f32_16x16x32_f16(av, *(const h8*)(bp + k),          a0, 0,0,0);
      a1 = __builtin_amdgcn_mfma_f32_16x16x32_f16(av, *(const h8*)(bp + 16*DIN + k), a1, 0,0,0);
      a2 = __builtin_amdgcn_mfma_f32_16x16x32_f16(av, *(const h8*)(bp + 32*DIN + k), a2, 0,0,0);
      a3 = __builtin_amdgcn_mfma_f32_16x16x32_f16(av, *(const h8*)(bp + 48*DIN + k), a3, 0,0,0);
    }
#pragma unroll
    for (int r = 0; r < 4; ++r) {
      int row = m0 + q * 4 + r;
      int c0 = n0 + ml;
      P.CIN[(size_t)row * HSZ + c0     ] = (_Float16)tanhf(a0[r] + P.b_cin[c0]);
      P.CIN[(size_t)row * HSZ + c0 + 16] = (_Float16)tanhf(a1[r] + P.b_cin[c0 + 16]);
      P.CIN[(size_t)row * HSZ + c0 + 32] = (_Float16)tanhf(a2[r] + P.b_cin[c0 + 32]);
      P.CIN[(size_t)row * HSZ + c0 + 48] = (_Float16)tanhf(a3[r] + P.b_cin[c0 + 48]);
    }
  }
}

__global__ __launch_bounds__(256) void init_kernel(P_t P) {
  int idx = blockIdx.x * 256 + threadIdx.x;
  if (idx < BSZ * HSZ) {
    P.HF32[idx] = 0.f;
    P.HF16[idx] = (_Float16)0.f;   // HF16[0] = h0 = 0
  }
  if (idx < NCTR) P.CTR[idx] = 0u;
}

// ---------------- main persistent dataflow kernel ----------------
__global__ __launch_bounds__(NTHR) void rnn_main(P_t P) {
  __shared__ __align__(16) _Float16 sm[SM_F16];
  __shared__ f4 red[8][64];
  __shared__ float sred[8];
  const int tid = threadIdx.x;
  const int b = blockIdx.x;
  const int lane = tid & 63;
  const int wv = tid >> 6;          // 0..15
  const int ml = lane & 15, q = lane >> 4;
  const int rep = b & 3;

  unsigned* CNT = P.CTR;
  unsigned* EPO = P.CTR + 8 * CLINE;
#define CNTB(k)  (CNT + (k) * CLINE)
#define EPOB(k)  (EPO + (k) * 4 * CLINE)
#define EPOL(k)  (EPO + ((k) * 4 + rep) * CLINE)
  // k: 0=CTA(z1,c) 1=CTB(z2) 2=CTC(PART) 3=CTD(gates) 4=CTE(h-state)

  // ---- stage weights into LDS, fragment-major ----
  if (b < 192) {
    const _Float16* W = (b < 64) ? P.WT1 : (b < 128) ? P.WT2 : P.WT3;
    const int j16 = b & 63;
#pragma unroll
    for (int rp = 0; rp < 2; ++rp) {
      int idx = tid + rp * 1024;
      int kk = idx >> 6, ln = idx & 63;
      int mlw = ln & 15, qw = ln >> 4;
      *(h8*)(sm + idx * 8) =
          *(const h8*)(W + (size_t)(16 * j16 + mlw) * HH2 + kk * 32 + qw * 8);
    }
  } else {
    const int i = b - 192;
#pragma unroll
    for (int s = 0; s < 3; ++s) {
      int g = 3 * i + s;
      const _Float16* src = (g < 96) ? (P.WTih + (size_t)(16 * g) * HSZ)
                                     : (P.WThh + (size_t)(16 * (g - 96)) * HSZ);
      int idx = tid;
      int kk = idx >> 6, ln = idx & 63;
      int mlw = ln & 15, qw = ln >> 4;
      *(h8*)(sm + s * 8192 + idx * 8) =
          *(const h8*)(src + (size_t)mlw * HSZ + kk * 32 + qw * 8);
    }
  }
  __syncthreads();

  if (b < 64) {
    // ======== W1 role: owns c-state in registers; 3-hop critical path ========
    const int tt = wv & 7, hf = wv >> 3;
    const int R = 16 * tt + ml;
    const int colb = 16 * b + ml;
    const float bia = P.b1[colb];
    const float b4v = P.b4[0];
    f4 cf[16];
#pragma unroll
    for (int i = 0; i < 16; ++i) cf[i] = (f4){0.f, 0.f, 0.f, 0.f};
    float n_r = 0.f;
    const bool pub = (tt == (b >> 3)) && ((ml >> 1) == (b & 7));  // rows 2b,2b+1

    for (int t = 0; t <= SLEN; ++t) {
      blk_wait(EPOL(2), (unsigned)t);   // alpha(t-1) partials (no WAR wait: COMlo versioned)
      if (t > 0) {
        f4 pr[4];
        lic_load4f4(pr, P.PART + (size_t)((t - 1) & 1) * BSZ * 64 + (size_t)R * 64 + q * 16);
        float s = pr[0][0] + pr[0][1] + pr[0][2] + pr[0][3]
                + pr[1][0] + pr[1][1] + pr[1][2] + pr[1][3]
                + pr[2][0] + pr[2][1] + pr[2][2] + pr[2][3]
                + pr[3][0] + pr[3][1] + pr[3][2] + pr[3][3];
        s += __shfl_xor(s, 16); s += __shfl_xor(s, 32);
        float lg = (s + b4v + P.LOGI[(size_t)(t - 1) * BSZ + R]) * 10.0f;
        float alpha = 1.f / (1.f + expf(-lg));
        float om = 1.f - alpha;
        float nom = n_r * om, nnew = nom + 1.f;
        n_r = nnew;
        const _Float16* cinp = P.CIN + ((size_t)(t - 1) * BSZ + R) * HSZ + hf * 256 + q * 8;
#pragma unroll
        for (int i = 0; i < 8; ++i) {
          h8 ci = *(const h8*)(cinp + i * 32);
#pragma unroll
          for (int j = 0; j < 4; ++j) {
            cf[2 * i][j]     = (cf[2 * i][j]     * nom + (float)ci[j])     / nnew;
            cf[2 * i + 1][j] = (cf[2 * i + 1][j] * nom + (float)ci[4 + j]) / nnew;
          }
        }
      }
      // publish c(t-1) into versioned COMlo[t]
      if (pub) {
        _Float16* cp = P.COMlo + (size_t)t * BSZ * HSZ
                     + (size_t)R * HSZ + hf * 256 + q * 8;
#pragma unroll
        for (int i = 0; i < 8; ++i) {
          h8 hv;
#pragma unroll
          for (int j = 0; j < 4; ++j) {
            hv[j]     = (_Float16)cf[2 * i][j];
            hv[4 + j] = (_Float16)cf[2 * i + 1][j];
          }
          lic_store16(cp + i * 32, hv);
        }
      }
      if (t == SLEN) { blk_arrive(CNTB(0), EPOB(0), 64u * (unsigned)(SLEN + 1) - 1u); break; }
      const _Float16* bfc = sm + (size_t)(hf * 8) * 512 + lane * 8;
      const _Float16* bfn = sm + (size_t)(16 + hf * 8) * 512 + lane * 8;
      const _Float16* cin2 = P.CIN + ((size_t)t * BSZ + R) * HSZ + hf * 256 + q * 8;
      f4 a = {0.f, 0.f, 0.f, 0.f};
#pragma unroll
      for (int i = 0; i < 8; ++i) {
        h8 av;
#pragma unroll
        for (int j = 0; j < 4; ++j) {
          av[j]     = (_Float16)cf[2 * i][j];
          av[4 + j] = (_Float16)cf[2 * i + 1][j];
        }
        a = mfma16(av, *(const h8*)(bfc + (size_t)i * 512), a);
      }
#pragma unroll
      for (int i = 0; i < 8; ++i)
        a = mfma16(*(const h8*)(cin2 + i * 32), *(const h8*)(bfn + (size_t)i * 512), a);
      if (hf) red[tt][lane] = a;
      __syncthreads();
      if (!hf) {
        f4 o = red[tt][lane];
#pragma unroll
        for (int j = 0; j < 4; ++j)
          lic_store2(P.Z1 + (size_t)t * BSZ * HH2
                     + (size_t)(tt * 16 + q * 4 + j) * HH2 + colb,
                     (_Float16)fmaxf(a[j] + o[j] + bia, 0.f));
      }
      blk_arrive(CNTB(0), EPOB(0), 64u * (unsigned)(t + 1) - 1u);
    }
  } else if (b < 192) {
    // ======== W2 / W3 roles (A via cached reads of versioned buffers) ========
    const int role = (b < 128) ? 1 : 2;
    const int cb = (role == 1) ? b - 64 : b - 128;
    const int colb = 16 * cb + ml;
    const float bia = (role == 1) ? P.b2[colb] : P.b3[colb];
    const float w4v = (role == 2) ? P.w4[colb] : 0.f;
    const int r = wv & 7, half = wv >> 3, m0 = r * 16;

    for (int t = 0; t < SLEN; ++t) {
      if (role == 1) {
        blk_wait(EPOL(0), (unsigned)(t + 1));
      } else {
        blk_wait(EPOL(1), (unsigned)(t + 1));
        blk_wait(EPOL(4), (unsigned)(t > 0 ? t - 1 : 0));   // PART[t&1] WAR
      }
      const _Float16* A = ((role == 1) ? P.Z1 : P.Z2) + (size_t)t * BSZ * HH2;
      f4 a = gemm_c512(A + (size_t)(m0 + ml) * HH2 + half * 512 + q * 8,
                       sm + (size_t)half * 16 * 512, lane);
      if (wv >= 8) red[r][lane] = a;
      __syncthreads();
      if (wv < 8) {
        f4 o = red[r][lane];
        if (role == 1) {
#pragma unroll
          for (int j = 0; j < 4; ++j)
            lic_store2(P.Z2 + (size_t)t * BSZ * HH2
                       + (size_t)(m0 + q * 4 + j) * HH2 + colb,
                       (_Float16)fmaxf(a[j] + o[j] + bia, 0.f));
        } else {
#pragma unroll
          for (int j = 0; j < 4; ++j) {
            float v = fmaxf(a[j] + o[j] + bia, 0.f) * w4v;
            v += __shfl_xor(v, 1); v += __shfl_xor(v, 2);
            v += __shfl_xor(v, 4); v += __shfl_xor(v, 8);
            if (ml == 0)
              lic_store4(P.PART + (size_t)(t & 1) * BSZ * 64
                         + (size_t)(m0 + q * 4 + j) * 64 + cb, v);
          }
        }
      }
      if (role == 1) blk_arrive(CNTB(1), EPOB(1), 64u * (unsigned)(t + 1) - 1u);
      else           blk_arrive(CNTB(2), EPOB(2), 64u * (unsigned)(t + 1) - 1u);
    }
  } else {
    // ======== gate role: gx/gh GEMMs + h-state for rows 2i,2i+1 ========
    const int i = b - 192;
    const bool isgx = (i < 32);
    const float* bsrc = isgx ? P.b_ih : P.b_hh;
    float* gbase = isgx ? P.GX : P.GH;
    const int i0 = isgx ? 3 * i : 3 * (i - 32);
    const int c0 = 16 * i0 + ml, c1 = 16 * (i0 + 1) + ml, c2 = 16 * (i0 + 2) + ml;
    const float bi0 = bsrc[c0], bi1 = bsrc[c1], bi2 = bsrc[c2];

    for (int t = 0; t < SLEN; ++t) {
      if (isgx) {
        blk_wait(EPOL(0), (unsigned)(t + 1));               // c(t-1) in COMlo[t]
        blk_wait(EPOL(4), (unsigned)(t > 0 ? t - 1 : 0));   // GX[t&1] WAR
      } else {
        blk_wait(EPOL(4), (unsigned)t);                     // h(t-1) in HF16[t]
      }
      const _Float16* Ag = (isgx ? P.COMlo : P.HF16) + (size_t)t * BSZ * HSZ;
      float* gdst = gbase + (size_t)(t & 1) * BSZ * GG3;
      if (wv < 8) {
        const int m0 = wv * 16;
        f4 a0, a1;
        gemm2_c512(Ag + (size_t)(m0 + ml) * HSZ + q * 8, sm, sm + 8192, lane, a0, a1);
#pragma unroll
        for (int j = 0; j < 4; ++j) {
          size_t rw = (size_t)(m0 + q * 4 + j) * GG3;
          lic_store4(gdst + rw + c0, a0[j] + bi0);
          lic_store4(gdst + rw + c1, a1[j] + bi1);
        }
      } else {
        const int m0 = (wv - 8) * 16;
        f4 a2 = gemm_c512(Ag + (size_t)(m0 + ml) * HSZ + q * 8, sm + 2 * 8192, lane);
#pragma unroll
        for (int j = 0; j < 4; ++j)
          lic_store4(gdst + (size_t)(m0 + q * 4 + j) * GG3 + c2, a2[j] + bi2);
      }
      blk_arrive(CNTB(3), EPOB(3), 64u * (unsigned)(t + 1) - 1u);
      blk_wait(EPOL(2), (unsigned)(t + 1));   // alpha(t) partials
      blk_wait(EPOL(3), (unsigned)(t + 1));   // gx(t)/gh(t)
      if (wv < 2) {
        int row = 2 * i + wv;
        float v = lic_load4(P.PART + (size_t)(t & 1) * BSZ * 64 + (size_t)row * 64 + lane);
#pragma unroll
        for (int off = 32; off > 0; off >>= 1) v += __shfl_xor(v, off);
        if (lane == 0) {
          float lg = (v + P.b4[0] + P.LOGI[t * BSZ + row]) * 10.0f;
          float alpha = 1.f / (1.f + expf(-lg));
          sred[wv * 4 + 0] = alpha;
          sred[wv * 4 + 1] = 1.f - alpha;
        }
      }
      __syncthreads();
      {
        int rr = tid >> 9, col = tid & 511, row = 2 * i + rr;
        float alpha = sred[rr * 4], om = sred[rr * 4 + 1];
        const float* gx = P.GX + (size_t)(t & 1) * BSZ * GG3;
        const float* gh = P.GH + (size_t)(t & 1) * BSZ * GG3;
        float g[6];
        lic_load_gates(g, gx + (size_t)row * GG3 + col + 512,
                          gh + (size_t)row * GG3 + col + 512);
        float rgate = 1.f / (1.f + expf(-(g[0] + g[3])));
        float zgate = 1.f / (1.f + expf(-(g[1] + g[4])));
        float ngate = tanhf(g[2] + rgate * g[5]);
        size_t ho = (size_t)row * HSZ + col;
        float h_old = P.HF32[ho];
        float hg = (1.f - zgate) * ngate + zgate * h_old;
        float hnew = h_old * om + alpha * hg;
        P.HF32[ho] = hnew;
        lic_store2(P.HF16 + (size_t)(t + 1) * BSZ * HSZ + ho, (_Float16)hnew);
      }
      blk_arrive(CNTB(4), EPOB(4), 64u * (unsigned)(t + 1) - 1u);
    }

    // ---- tail: final gate GEMMs (COMlo[SLEN]=c(255), HF16[SLEN]=h(255)) ----
    if (isgx) {
      blk_wait(EPOL(0), (unsigned)(SLEN + 1));
      blk_wait(EPOL(4), (unsigned)SLEN);   // all state(255) done before GX[0] overwrite
    } else {
      blk_wait(EPOL(4), (unsigned)SLEN);
    }
    {
      const _Float16* Ag = (isgx ? P.COMlo : P.HF16) + (size_t)SLEN * BSZ * HSZ;
      float* gdst = gbase;                  // parity 0 scratch for tail
      if (wv < 8) {
        const int m0 = wv * 16;
        f4 a0, a1;
        gemm2_c512(Ag + (size_t)(m0 + ml) * HSZ + q * 8, sm, sm + 8192, lane, a0, a1);
#pragma unroll
        for (int j = 0; j < 4; ++j) {
          size_t rw = (size_t)(m0 + q * 4 + j) * GG3;
          lic_store4(gdst + rw + c0, a0[j] + bi0);
          lic_store4(gdst + rw + c1, a1[j] + bi1);
        }
      } else {
        const int m0 = (wv - 8) * 16;
        f4 a2 = gemm_c512(Ag + (size_t)(m0 + ml) * HSZ + q * 8, sm + 2 * 8192, lane);
#pragma unroll
        for (int j = 0; j < 4; ++j)
          lic_store4(gdst + (size_t)(m0 + q * 4 + j) * GG3 + c2, a2[j] + bi2);
      }
    }
    blk_arrive(CNTB(3), EPOB(3), 64u * (unsigned)(SLEN + 1) - 1u);
    blk_wait(EPOL(3), (unsigned)(SLEN + 1));
    __syncthreads();  // weights done; reuse sm as float hfin[1024]
    {
      float* hf = (float*)sm;
      int rr = tid >> 9, col = tid & 511, row = 2 * i + rr;
      float g[6];
      lic_load_gates(g, P.GX + (size_t)row * GG3 + col + 512,
                        P.GH + (size_t)row * GG3 + col + 512);
      float rgate = 1.f / (1.f + expf(-(g[0] + g[3])));
      float zgate = 1.f / (1.f + expf(-(g[1] + g[4])));
      float ngate = tanhf(g[2] + rgate * g[5]);
      float h_old = P.HF32[(size_t)row * HSZ + col];
      hf[tid] = (1.f - zgate) * ngate + zgate * h_old;
    }
    __syncthreads();
    if (wv < 2) {
      const float* hf = (const float*)sm;
      int row = 2 * i + wv;
      float accs[OSZ];
#pragma unroll
      for (int c = 0; c < OSZ; ++c) accs[c] = 0.f;
#pragma unroll
      for (int j = 0; j < 8; ++j) {
        float hv = hf[wv * 512 + lane * 8 + j];
        const float* wr = P.w_out + (size_t)(lane * 8 + j) * OSZ;
#pragma unroll
        for (int c = 0; c < OSZ; ++c) accs[c] += hv * wr[c];
      }
#pragma unroll
      for (int c = 0; c < OSZ; ++c) {
        float v = accs[c];
#pragma unroll
        for (int off = 32; off > 0; off >>= 1) v += __shfl_xor(v, off);
        if (lane == 0) P.out[row * OSZ + c] = v + P.b_out[c];
      }
    }
  }
}

// ---------------- host ----------------
extern "C" void kernel_launch(void* const* d_in, const int* in_sizes, int n_in,
                              void* d_out, int out_size, void* d_ws, size_t ws_size,
                              hipStream_t stream) {
  const float* x     = (const float*)d_in[0];
  const float* noise = (const float*)d_in[1];
  const float* w_cin = (const float*)d_in[2];
  const float* b_cin = (const float*)d_in[3];
  const float* w1    = (const float*)d_in[4];
  const float* b1    = (const float*)d_in[5];
  const float* w2    = (const float*)d_in[6];
  const float* b2    = (const float*)d_in[7];
  const float* w3    = (const float*)d_in[8];
  const float* b3    = (const float*)d_in[9];
  const float* w4    = (const float*)d_in[10];
  const float* b4    = (const float*)d_in[11];
  const float* w_ih  = (const float*)d_in[12];
  const float* b_ih  = (const float*)d_in[13];
  const float* w_hh  = (const float*)d_in[14];
  const float* b_hh  = (const float*)d_in[15];
  const float* w_out = (const float*)d_in[16];
  const float* b_out = (const float*)d_in[17];

  char* ws = (char*)d_ws;
  size_t off = 0;
  auto alloc = [&](size_t bytes) -> void* {
    void* p = ws + off;
    off = (off + bytes + 255) & ~(size_t)255;
    return p;
  };

  P_t P;
  P.x = x; P.noise = noise; P.b_cin = b_cin; P.b1 = b1; P.b2 = b2; P.b3 = b3;
  P.w4 = w4; P.b4 = b4; P.b_ih = b_ih; P.b_hh = b_hh; P.w_out = w_out; P.b_out = b_out;
  P.WT1   = (_Float16*)alloc((size_t)HH2 * HH2 * 2);
  P.WT2   = (_Float16*)alloc((size_t)HH2 * HH2 * 2);
  P.WT3   = (_Float16*)alloc((size_t)HH2 * HH2 * 2);
  P.WTih  = (_Float16*)alloc((size_t)GG3 * HSZ * 2);
  P.WThh  = (_Float16*)alloc((size_t)GG3 * HSZ * 2);
  P.WTcin = (_Float16*)alloc((size_t)HSZ * DIN * 2);
  P.CIN   = (_Float16*)alloc((size_t)SLEN * BSZ * HSZ * 2);
  // step-versioned buffers (write-once addresses; ~195 MB total)
  P.COMlo = (_Float16*)alloc((size_t)(SLEN + 1) * BSZ * HSZ * 2);
  P.Z1    = (_Float16*)alloc((size_t)SLEN * BSZ * HH2 * 2);
  P.Z2    = (_Float16*)alloc((size_t)SLEN * BSZ * HH2 * 2);
  P.HF16  = (_Float16*)alloc((size_t)(SLEN + 1) * BSZ * HSZ * 2);
  P.LOGI  = (float*)alloc((size_t)SLEN * BSZ * 4);
  P.GX    = (float*)alloc((size_t)2 * BSZ * GG3 * 4);
  P.GH    = (float*)alloc((size_t)2 * BSZ * GG3 * 4);
  P.PART  = (float*)alloc((size_t)2 * BSZ * 64 * 4);
  P.HF32  = (float*)alloc((size_t)BSZ * HSZ * 4);
  P.CTR   = (unsigned*)alloc(NCTR * 4);
  P.out   = (float*)d_out;

  transpose_cvt<<<(HH2 / 32) * (HH2 / 32), 256, 0, stream>>>(w1, P.WT1, HH2, HH2);
  transpose_cvt<<<(HH2 / 32) * (HH2 / 32), 256, 0, stream>>>(w2, P.WT2, HH2, HH2);
  transpose_cvt<<<(HH2 / 32) * (HH2 / 32), 256, 0, stream>>>(w3, P.WT3, HH2, HH2);
  transpose_cvt<<<(GG3 / 32) * (HSZ / 32), 256, 0, stream>>>(w_ih, P.WTih, HSZ, GG3);
  transpose_cvt<<<(GG3 / 32) * (HSZ / 32), 256, 0, stream>>>(w_hh, P.WThh, HSZ, GG3);
  transpose_cvt<<<(HSZ / 32) * (DIN / 32), 256, 0, stream>>>(w_cin, P.WTcin, DIN, HSZ);

  cin_kernel<<<1024, 256, 0, stream>>>(P);
  init_kernel<<<256, 256, 0, stream>>>(P);
  rnn_main<<<NBLK, NTHR, 0, stream>>>(P);
}

// Round 15
// 6966.168 us; speedup vs baseline: 1.3218x; 1.2029x over previous
//
#include <hip/hip_runtime.h>
#include <math.h>

// Problem dims
#define SLEN 256
#define BSZ  128
#define DIN  128
#define HSZ  512
#define HH2  1024
#define GG3  1536
#define OSZ  25

typedef _Float16 h8 __attribute__((ext_vector_type(8)));
typedef float    f4 __attribute__((ext_vector_type(4)));

struct P_t {
  const float *x, *noise, *b_cin, *b1, *b2, *b3, *w4, *b4, *b_ih, *b_hh, *w_out, *b_out;
  _Float16 *WT1, *WT2, *WT3, *WTih, *WThh, *WTcin;   // row-major [N][K] (setup)
  _Float16 *FW1, *FW2, *FW3, *FWih, *FWhh;           // fragment-major (hot path)
  _Float16 *CIN, *COMlo, *Z1, *Z2, *HF16;
  float *LOGI, *GX, *GH, *PART, *HF32, *CF32, *NF32;
  float *out;
};

__device__ __forceinline__ f4 mfma16(h8 a, h8 b, f4 c) {
  return __builtin_amdgcn_mfma_f32_16x16x32_f16(a, b, c, 0, 0, 0);
}

// ---------------- setup kernels ----------------
__global__ __launch_bounds__(256) void transpose_cvt(const float* __restrict__ src,
    _Float16* __restrict__ dst, int K, int N) {
  __shared__ float tl[32][33];
  int nt = N >> 5;
  int bx = blockIdx.x % nt, by = blockIdx.x / nt;
  int n0 = bx << 5, k0 = by << 5;
  int tx = threadIdx.x & 31, ty = threadIdx.x >> 5;
#pragma unroll
  for (int i = 0; i < 4; ++i) {
    int r = ty + (i << 3);
    tl[r][tx] = src[(size_t)(k0 + r) * N + n0 + tx];
  }
  __syncthreads();
#pragma unroll
  for (int i = 0; i < 4; ++i) {
    int r = ty + (i << 3);
    dst[(size_t)(n0 + r) * K + k0 + tx] = (_Float16)tl[tx][r];
  }
}

// [N][K] row-major -> fragment-major: dst[(ct*(K/32)+i)*512 + (q*16+ml)*8 + j]
//   = src[(ct*16+ml)*K + i*32 + q*8 + j].  Makes B-loads fully coalesced.
__global__ __launch_bounds__(512) void fragpack(const _Float16* __restrict__ src,
    _Float16* __restrict__ dst, int K) {
  int ct = blockIdx.x;
  int chunks = (K / 32) * 64;
  for (int idx = threadIdx.x; idx < chunks; idx += 512) {
    int i = idx >> 6, lane = idx & 63;
    int mlw = lane & 15, qw = lane >> 4;
    *(h8*)(dst + ((size_t)ct * (K / 32) + i) * 512 + (size_t)lane * 8) =
        *(const h8*)(src + ((size_t)ct * 16 + mlw) * K + i * 32 + qw * 8);
  }
}

__global__ __launch_bounds__(256) void cin_kernel(P_t P) {
  int tid = blockIdx.x * blockDim.x + threadIdx.x;
  if (tid < SLEN * BSZ) {
    float u = P.noise[tid];
    P.LOGI[tid] = logf(u) - log1pf(-u);
  }
  int gw = tid >> 6, lane = tid & 63;
  int nw = (gridDim.x * blockDim.x) >> 6;
  int ml = lane & 15, q = lane >> 4;
  const int MT = (SLEN * BSZ) / 16;
  for (int tt = gw; tt < MT * 8; tt += nw) {
    int mt = tt & (MT - 1), nt = tt / MT;
    int m0 = mt * 16, n0 = nt * 64;
    int m = m0 + ml, b = m & 127, s = m >> 7;
    const float* ap = P.x + ((size_t)b * SLEN + s) * DIN + q * 8;
    const _Float16* bp = P.WTcin + (size_t)(n0 + ml) * DIN + q * 8;
    f4 a0 = {0,0,0,0}, a1 = a0, a2 = a0, a3 = a0;
#pragma unroll
    for (int k = 0; k < DIN; k += 32) {
      f4 lo = *(const f4*)(ap + k);
      f4 hi = *(const f4*)(ap + k + 4);
      h8 av;
      av[0] = (_Float16)lo[0]; av[1] = (_Float16)lo[1];
      av[2] = (_Float16)lo[2]; av[3] = (_Float16)lo[3];
      av[4] = (_Float16)hi[0]; av[5] = (_Float16)hi[1];
      av[6] = (_Float16)hi[2]; av[7] = (_Float16)hi[3];
      a0 = mfma16(av, *(const h8*)(bp + k),            a0);
      a1 = mfma16(av, *(const h8*)(bp + 16*DIN + k),   a1);
      a2 = mfma16(av, *(const h8*)(bp + 32*DIN + k),   a2);
      a3 = mfma16(av, *(const h8*)(bp + 48*DIN + k),   a3);
    }
#pragma unroll
    for (int r = 0; r < 4; ++r) {
      int row = m0 + q * 4 + r;
      int c0 = n0 + ml;
      P.CIN[(size_t)row * HSZ + c0     ] = (_Float16)tanhf(a0[r] + P.b_cin[c0]);
      P.CIN[(size_t)row * HSZ + c0 + 16] = (_Float16)tanhf(a1[r] + P.b_cin[c0 + 16]);
      P.CIN[(size_t)row * HSZ + c0 + 32] = (_Float16)tanhf(a2[r] + P.b_cin[c0 + 32]);
      P.CIN[(size_t)row * HSZ + c0 + 48] = (_Float16)tanhf(a3[r] + P.b_cin[c0 + 48]);
    }
  }
}

__global__ __launch_bounds__(256) void init_kernel(P_t P) {
  int idx = blockIdx.x * 256 + threadIdx.x;
  if (idx < BSZ * HSZ) {
    P.HF32[idx] = 0.f; P.CF32[idx] = 0.f;
    P.HF16[idx] = (_Float16)0.f; P.COMlo[idx] = (_Float16)0.f;
  }
  if (idx < BSZ) P.NF32[idx] = 0.f;
}

// ---------------- per-step kernels (graph-pipelined, all cached) ----------------
// step_a: z1 = relu([c,cin(t)]@W1+b1)  (tiles 0..511)
//         gx = c@Wih + b_ih            (tiles 512..1279)
//         gh = h@Whh + b_hh            (tiles 1280..2047)
__global__ __launch_bounds__(256) void step_a(P_t P, int t, int base) {
  const int tid = threadIdx.x;
  const int lane = tid & 63, wv = tid >> 6;
  const int ml = lane & 15, q = lane >> 4;
  const int g = base + blockIdx.x * 4 + wv;
  f4 acc = {0.f, 0.f, 0.f, 0.f};
  if (g < 512) {
    int rt = g & 7, ct = g >> 3;
    int m0 = rt * 16, col = ct * 16 + ml;
    const _Float16* a0 = P.COMlo + (size_t)(m0 + ml) * HSZ + q * 8;
    const _Float16* a1 = P.CIN + ((size_t)t * BSZ + m0 + ml) * HSZ + q * 8;
    const _Float16* bp = P.FW1 + (size_t)ct * 32 * 512 + (size_t)lane * 8;
#pragma unroll
    for (int i = 0; i < 16; ++i)
      acc = mfma16(*(const h8*)(a0 + i * 32), *(const h8*)(bp + (size_t)i * 512), acc);
#pragma unroll
    for (int i = 0; i < 16; ++i)
      acc = mfma16(*(const h8*)(a1 + i * 32), *(const h8*)(bp + (size_t)(16 + i) * 512), acc);
    float bia = P.b1[col];
#pragma unroll
    for (int j = 0; j < 4; ++j)
      P.Z1[(size_t)(m0 + q * 4 + j) * HH2 + col] = (_Float16)fmaxf(acc[j] + bia, 0.f);
  } else if (g < 1280) {
    int u = g - 512, rt = u & 7, ct = u >> 3;
    int m0 = rt * 16, col = ct * 16 + ml;
    const _Float16* a0 = P.COMlo + (size_t)(m0 + ml) * HSZ + q * 8;
    const _Float16* bp = P.FWih + (size_t)ct * 16 * 512 + (size_t)lane * 8;
#pragma unroll
    for (int i = 0; i < 16; ++i)
      acc = mfma16(*(const h8*)(a0 + i * 32), *(const h8*)(bp + (size_t)i * 512), acc);
    float bia = P.b_ih[col];
#pragma unroll
    for (int j = 0; j < 4; ++j)
      P.GX[(size_t)(m0 + q * 4 + j) * GG3 + col] = acc[j] + bia;
  } else {
    int u = g - 1280, rt = u & 7, ct = u >> 3;
    int m0 = rt * 16, col = ct * 16 + ml;
    const _Float16* a0 = P.HF16 + (size_t)(m0 + ml) * HSZ + q * 8;
    const _Float16* bp = P.FWhh + (size_t)ct * 16 * 512 + (size_t)lane * 8;
#pragma unroll
    for (int i = 0; i < 16; ++i)
      acc = mfma16(*(const h8*)(a0 + i * 32), *(const h8*)(bp + (size_t)i * 512), acc);
    float bia = P.b_hh[col];
#pragma unroll
    for (int j = 0; j < 4; ++j)
      P.GH[(size_t)(m0 + q * 4 + j) * GG3 + col] = acc[j] + bia;
  }
}

// step_b: z2 = relu(z1@W2+b2)
__global__ __launch_bounds__(256) void step_b(P_t P) {
  const int tid = threadIdx.x;
  const int lane = tid & 63, wv = tid >> 6;
  const int ml = lane & 15, q = lane >> 4;
  const int g = blockIdx.x * 4 + wv;
  int rt = g & 7, ct = g >> 3;
  int m0 = rt * 16, col = ct * 16 + ml;
  const _Float16* a0 = P.Z1 + (size_t)(m0 + ml) * HH2 + q * 8;
  const _Float16* bp = P.FW2 + (size_t)ct * 32 * 512 + (size_t)lane * 8;
  f4 acc = {0.f, 0.f, 0.f, 0.f};
#pragma unroll
  for (int i = 0; i < 32; ++i)
    acc = mfma16(*(const h8*)(a0 + i * 32), *(const h8*)(bp + (size_t)i * 512), acc);
  float bia = P.b2[col];
#pragma unroll
  for (int j = 0; j < 4; ++j)
    P.Z2[(size_t)(m0 + q * 4 + j) * HH2 + col] = (_Float16)fmaxf(acc[j] + bia, 0.f);
}

// step_c: PART[ct][row] = sum over this col-tile of relu(z2@W3+b3)*w4
__global__ __launch_bounds__(256) void step_c(P_t P) {
  const int tid = threadIdx.x;
  const int lane = tid & 63, wv = tid >> 6;
  const int ml = lane & 15, q = lane >> 4;
  const int g = blockIdx.x * 4 + wv;
  int rt = g & 7, ct = g >> 3;
  int m0 = rt * 16, col = ct * 16 + ml;
  const _Float16* a0 = P.Z2 + (size_t)(m0 + ml) * HH2 + q * 8;
  const _Float16* bp = P.FW3 + (size_t)ct * 32 * 512 + (size_t)lane * 8;
  f4 acc = {0.f, 0.f, 0.f, 0.f};
#pragma unroll
  for (int i = 0; i < 32; ++i)
    acc = mfma16(*(const h8*)(a0 + i * 32), *(const h8*)(bp + (size_t)i * 512), acc);
  float bia = P.b3[col], w4v = P.w4[col];
#pragma unroll
  for (int j = 0; j < 4; ++j) {
    float v = fmaxf(acc[j] + bia, 0.f) * w4v;
    v += __shfl_xor(v, 1); v += __shfl_xor(v, 2);
    v += __shfl_xor(v, 4); v += __shfl_xor(v, 8);
    if (ml == 0) P.PART[(size_t)ct * BSZ + m0 + q * 4 + j] = v;
  }
}

// step_d: alpha(t) + state update; one row per block
__global__ __launch_bounds__(512) void step_d(P_t P, int t) {
  __shared__ float sa[4];
  const int r = blockIdx.x, tid = threadIdx.x;
  if (tid < 64) {
    float v = P.PART[(size_t)tid * BSZ + r];
#pragma unroll
    for (int off = 32; off > 0; off >>= 1) v += __shfl_xor(v, off);
    if (tid == 0) {
      float lg = (v + P.b4[0] + P.LOGI[(size_t)t * BSZ + r]) * 10.0f;
      float alpha = 1.f / (1.f + expf(-lg));
      float om = 1.f - alpha;
      float n_old = P.NF32[r];
      float nnew = n_old * om + 1.f;
      P.NF32[r] = nnew;
      sa[0] = alpha; sa[1] = om; sa[2] = n_old * om; sa[3] = nnew;
    }
  }
  __syncthreads();
  float alpha = sa[0], om = sa[1], nom = sa[2], nnew = sa[3];
  int col = tid;
  size_t go = (size_t)r * GG3 + col;
  float xr = P.GX[go], xz = P.GX[go + 512], xn = P.GX[go + 1024];
  float hr = P.GH[go], hz = P.GH[go + 512], hn = P.GH[go + 1024];
  float rg = 1.f / (1.f + expf(-(xr + hr)));
  float zg = 1.f / (1.f + expf(-(xz + hz)));
  float ng = tanhf(xn + rg * hn);
  size_t ho = (size_t)r * HSZ + col;
  float h_old = P.HF32[ho];
  float hg = (1.f - zg) * ng + zg * h_old;
  float hnew = h_old * om + alpha * hg;
  P.HF32[ho] = hnew; P.HF16[ho] = (_Float16)hnew;
  float c_old = P.CF32[ho];
  float cin_t = (float)P.CIN[((size_t)t * BSZ + r) * HSZ + col];
  float cnew = (c_old * nom + cin_t) / nnew;
  P.CF32[ho] = cnew; P.COMlo[ho] = (_Float16)cnew;
}

// final: hfin = GRU(c255,h255) gates -> out = hfin@w_out + b_out
__global__ __launch_bounds__(512) void final_kernel(P_t P) {
  __shared__ float hf[512];
  const int r = blockIdx.x, tid = threadIdx.x;
  const int lane = tid & 63, wv = tid >> 6;
  {
    int col = tid;
    size_t go = (size_t)r * GG3 + col;
    float xr = P.GX[go], xz = P.GX[go + 512], xn = P.GX[go + 1024];
    float hr = P.GH[go], hz = P.GH[go + 512], hn = P.GH[go + 1024];
    float rg = 1.f / (1.f + expf(-(xr + hr)));
    float zg = 1.f / (1.f + expf(-(xz + hz)));
    float ng = tanhf(xn + rg * hn);
    float h_old = P.HF32[(size_t)r * HSZ + col];
    hf[col] = (1.f - zg) * ng + zg * h_old;
  }
  __syncthreads();
  for (int c = wv; c < OSZ; c += 8) {
    float v = 0.f;
#pragma unroll
    for (int j = 0; j < 8; ++j)
      v += hf[lane + 64 * j] * P.w_out[(size_t)(lane + 64 * j) * OSZ + c];
#pragma unroll
    for (int off = 32; off > 0; off >>= 1) v += __shfl_xor(v, off);
    if (lane == 0) P.out[r * OSZ + c] = v + P.b_out[c];
  }
}

// ---------------- host ----------------
extern "C" void kernel_launch(void* const* d_in, const int* in_sizes, int n_in,
                              void* d_out, int out_size, void* d_ws, size_t ws_size,
                              hipStream_t stream) {
  const float* x     = (const float*)d_in[0];
  const float* noise = (const float*)d_in[1];
  const float* w_cin = (const float*)d_in[2];
  const float* b_cin = (const float*)d_in[3];
  const float* w1    = (const float*)d_in[4];
  const float* b1    = (const float*)d_in[5];
  const float* w2    = (const float*)d_in[6];
  const float* b2    = (const float*)d_in[7];
  const float* w3    = (const float*)d_in[8];
  const float* b3    = (const float*)d_in[9];
  const float* w4    = (const float*)d_in[10];
  const float* b4    = (const float*)d_in[11];
  const float* w_ih  = (const float*)d_in[12];
  const float* b_ih  = (const float*)d_in[13];
  const float* w_hh  = (const float*)d_in[14];
  const float* b_hh  = (const float*)d_in[15];
  const float* w_out = (const float*)d_in[16];
  const float* b_out = (const float*)d_in[17];

  char* ws = (char*)d_ws;
  size_t off = 0;
  auto alloc = [&](size_t bytes) -> void* {
    void* p = ws + off;
    off = (off + bytes + 255) & ~(size_t)255;
    return p;
  };

  P_t P;
  P.x = x; P.noise = noise; P.b_cin = b_cin; P.b1 = b1; P.b2 = b2; P.b3 = b3;
  P.w4 = w4; P.b4 = b4; P.b_ih = b_ih; P.b_hh = b_hh; P.w_out = w_out; P.b_out = b_out;
  P.WT1   = (_Float16*)alloc((size_t)HH2 * HH2 * 2);
  P.WT2   = (_Float16*)alloc((size_t)HH2 * HH2 * 2);
  P.WT3   = (_Float16*)alloc((size_t)HH2 * HH2 * 2);
  P.WTih  = (_Float16*)alloc((size_t)GG3 * HSZ * 2);
  P.WThh  = (_Float16*)alloc((size_t)GG3 * HSZ * 2);
  P.WTcin = (_Float16*)alloc((size_t)HSZ * DIN * 2);
  P.FW1   = (_Float16*)alloc((size_t)HH2 * HH2 * 2);
  P.FW2   = (_Float16*)alloc((size_t)HH2 * HH2 * 2);
  P.FW3   = (_Float16*)alloc((size_t)HH2 * HH2 * 2);
  P.FWih  = (_Float16*)alloc((size_t)GG3 * HSZ * 2);
  P.FWhh  = (_Float16*)alloc((size_t)GG3 * HSZ * 2);
  P.CIN   = (_Float16*)alloc((size_t)SLEN * BSZ * HSZ * 2);
  P.COMlo = (_Float16*)alloc((size_t)BSZ * HSZ * 2);
  P.Z1    = (_Float16*)alloc((size_t)BSZ * HH2 * 2);
  P.Z2    = (_Float16*)alloc((size_t)BSZ * HH2 * 2);
  P.HF16  = (_Float16*)alloc((size_t)BSZ * HSZ * 2);
  P.LOGI  = (float*)alloc((size_t)SLEN * BSZ * 4);
  P.GX    = (float*)alloc((size_t)BSZ * GG3 * 4);
  P.GH    = (float*)alloc((size_t)BSZ * GG3 * 4);
  P.PART  = (float*)alloc((size_t)64 * BSZ * 4);
  P.HF32  = (float*)alloc((size_t)BSZ * HSZ * 4);
  P.CF32  = (float*)alloc((size_t)BSZ * HSZ * 4);
  P.NF32  = (float*)alloc((size_t)BSZ * 4);
  P.out   = (float*)d_out;

  transpose_cvt<<<(HH2/32)*(HH2/32), 256, 0, stream>>>(w1, P.WT1, HH2, HH2);
  transpose_cvt<<<(HH2/32)*(HH2/32), 256, 0, stream>>>(w2, P.WT2, HH2, HH2);
  transpose_cvt<<<(HH2/32)*(HH2/32), 256, 0, stream>>>(w3, P.WT3, HH2, HH2);
  transpose_cvt<<<(GG3/32)*(HSZ/32), 256, 0, stream>>>(w_ih, P.WTih, HSZ, GG3);
  transpose_cvt<<<(GG3/32)*(HSZ/32), 256, 0, stream>>>(w_hh, P.WThh, HSZ, GG3);
  transpose_cvt<<<(HSZ/32)*(DIN/32), 256, 0, stream>>>(w_cin, P.WTcin, DIN, HSZ);
  fragpack<<<HH2/16, 512, 0, stream>>>(P.WT1, P.FW1, HH2);
  fragpack<<<HH2/16, 512, 0, stream>>>(P.WT2, P.FW2, HH2);
  fragpack<<<HH2/16, 512, 0, stream>>>(P.WT3, P.FW3, HH2);
  fragpack<<<GG3/16, 512, 0, stream>>>(P.WTih, P.FWih, HSZ);
  fragpack<<<GG3/16, 512, 0, stream>>>(P.WThh, P.FWhh, HSZ);

  cin_kernel<<<1024, 256, 0, stream>>>(P);
  init_kernel<<<256, 256, 0, stream>>>(P);

  for (int t = 0; t < SLEN; ++t) {
    step_a<<<512, 256, 0, stream>>>(P, t, 0);
    step_b<<<128, 256, 0, stream>>>(P);
    step_c<<<128, 256, 0, stream>>>(P);
    step_d<<<BSZ, 512, 0, stream>>>(P, t);
  }
  step_a<<<384, 256, 0, stream>>>(P, 0, 512);   // final gates from c(255), h(255)
  final_kernel<<<BSZ, 512, 0, stream>>>(P);
}